// Round 7
// baseline (320.439 us; speedup 1.0000x reference)
//
#include <hip/hip_runtime.h>

typedef unsigned short ushort_t;
typedef __bf16 bf16x8 __attribute__((ext_vector_type(8)));
typedef float floatx4 __attribute__((ext_vector_type(4)));

#define B_WIN 192
#define NTOK 256
#define CDIM 256
#define NHEAD 8
#define HDIM 32
#define NWIN 64
#define MROWS (B_WIN * NTOK)   // 49152

__device__ __forceinline__ float bf2f(unsigned int b) {
  unsigned int u = (b & 0xffffu) << 16;
  float f; __builtin_memcpy(&f, &u, 4); return f;
}
__device__ __forceinline__ ushort_t f2bf(float f) {
  unsigned int u; __builtin_memcpy(&u, &f, 4);
  u = (u + 0x7fffu + ((u >> 16) & 1u)) >> 16;
  return (ushort_t)u;
}
__device__ __forceinline__ bf16x8 ldg8(const ushort_t* p) {
  return *reinterpret_cast<const bf16x8*>(p);
}
__device__ __forceinline__ void async_copy16(const void* g, void* l) {
  __builtin_amdgcn_global_load_lds(
      (const __attribute__((address_space(1))) unsigned int*)g,
      (__attribute__((address_space(3))) unsigned int*)l, 16, 0, 0);
}

// ---------------- kernel 0a: fp32 -> bf16 conversion ------------------------
__global__ __launch_bounds__(256) void cvt_f32_bf16(const float* __restrict__ src,
                                                    ushort_t* __restrict__ dst, int n8) {
  int t = blockIdx.x * 256 + threadIdx.x;
  if (t >= n8) return;
  const float4* s = reinterpret_cast<const float4*>(src) + (size_t)t * 2;
  float4 v0 = s[0], v1 = s[1];
  union { ushort_t u[8]; uint4 v; } pk;
  pk.u[0] = f2bf(v0.x); pk.u[1] = f2bf(v0.y); pk.u[2] = f2bf(v0.z); pk.u[3] = f2bf(v0.w);
  pk.u[4] = f2bf(v1.x); pk.u[5] = f2bf(v1.y); pk.u[6] = f2bf(v1.z); pk.u[7] = f2bf(v1.w);
  reinterpret_cast<uint4*>(dst)[t] = pk.v;
}

// ---------------- kernel 0b: fp32 weights -> bf16 MFMA-TILED ----------------
__global__ __launch_bounds__(256) void cvt_tile_w(const float* __restrict__ src,
                                                  ushort_t* __restrict__ dst, int n) {
  int t = blockIdx.x * 256 + threadIdx.x;
  if (t >= n) return;
  int col = t >> 5;
  int kk = (t & 31) * 8;
  const float4* s = reinterpret_cast<const float4*>(src + (size_t)col * 256 + kk);
  float4 v0 = s[0], v1 = s[1];
  union { ushort_t u[8]; uint4 v; } pk;
  pk.u[0] = f2bf(v0.x); pk.u[1] = f2bf(v0.y); pk.u[2] = f2bf(v0.z); pk.u[3] = f2bf(v0.w);
  pk.u[4] = f2bf(v1.x); pk.u[5] = f2bf(v1.y); pk.u[6] = f2bf(v1.z); pk.u[7] = f2bf(v1.w);
  size_t base = (size_t)(((col >> 4) * 8 + (kk >> 5)) * 512 + ((kk >> 3) & 3) * 128 + (col & 15) * 8);
  *reinterpret_cast<uint4*>(dst + base) = pk.v;
}

// ---------------- kernel 1: bias+mask, per-lane-dense TILED bf16 ------------
// bm_t[win][h][row][qd][f][i] = bias+mask at (row, col=f*16+qd*4+i).
// Attn lane (ln,qd) reads its 64 values as 128B contiguous (8x uint4).
// Thread handles 8 cols (two 4-runs) x 1 head -> one uint4 store.
__global__ __launch_bounds__(256) void bm_prep(const int* __restrict__ idx,
                                               const float* __restrict__ table,
                                               const float* __restrict__ mask,
                                               ushort_t* __restrict__ bm) {
  int win = blockIdx.x;     // 0..63
  int row = blockIdx.y;     // 0..255
  int t = threadIdx.x;
  int qd = t & 3, g = (t >> 2) & 7, h = t >> 5;
  int jA = g * 32 + qd * 4;       // f = 2g
  int jB = jA + 16;               // f = 2g+1
  const int* ip = idx + row * 256;
  int4 iA = *reinterpret_cast<const int4*>(ip + jA);
  int4 iB = *reinterpret_cast<const int4*>(ip + jB);
  const float* mp = mask + ((size_t)(win * 256 + row) << 8);
  float4 mA = *reinterpret_cast<const float4*>(mp + jA);
  float4 mB = *reinterpret_cast<const float4*>(mp + jB);
  union { ushort_t u[8]; uint4 v; } pk;
  pk.u[0] = f2bf(table[iA.x * NHEAD + h] + mA.x);
  pk.u[1] = f2bf(table[iA.y * NHEAD + h] + mA.y);
  pk.u[2] = f2bf(table[iA.z * NHEAD + h] + mA.z);
  pk.u[3] = f2bf(table[iA.w * NHEAD + h] + mA.w);
  pk.u[4] = f2bf(table[iB.x * NHEAD + h] + mB.x);
  pk.u[5] = f2bf(table[iB.y * NHEAD + h] + mB.y);
  pk.u[6] = f2bf(table[iB.z * NHEAD + h] + mB.z);
  pk.u[7] = f2bf(table[iB.w * NHEAD + h] + mB.w);
  *reinterpret_cast<uint4*>(bm + ((size_t)(win * 8 + h) << 16) + row * 256 + qd * 64 + g * 8) = pk.v;
}

// ---------------- kernel 2: QKV GEMM, B in LDS, C^T epilogue for q/k --------
__global__ __launch_bounds__(256) void qkv_gemm(
    const ushort_t* __restrict__ x, const ushort_t* __restrict__ wt,
    const float* __restrict__ qkvb, ushort_t* __restrict__ qws,
    ushort_t* __restrict__ kws, ushort_t* __restrict__ vtws) {
  __shared__ __align__(16) ushort_t bsh[128 * 256];   // 64 KB
  const int lane = threadIdx.x & 63;
  const int wv = threadIdx.x >> 6;
  const int ln = lane & 15, qd = lane >> 4;
  const int row0 = blockIdx.x * 128 + (wv >> 1) * 64;
  const int col0 = blockIdx.y * 128;
  const int colw = col0 + (wv & 1) * 64;
  const int sblk = blockIdx.y >> 1;   // 0=q 1=k 2=v

  {
    const char* g = (const char*)(wt + (size_t)col0 * 256);
    #pragma unroll
    for (int r = 0; r < 16; ++r) {
      int off = r * 4096 + wv * 1024;
      async_copy16(g + off + lane * 16, (char*)bsh + off);
    }
  }
  __syncthreads();

  floatx4 acc[4][4];
  #pragma unroll
  for (int rt = 0; rt < 4; ++rt)
    #pragma unroll
    for (int ct = 0; ct < 4; ++ct)
      acc[rt][ct] = floatx4{0.f, 0.f, 0.f, 0.f};

  const ushort_t* ap = x + (size_t)(row0 + ln) * 256 + qd * 8;
  bf16x8 abuf[2][4];
  #pragma unroll
  for (int t = 0; t < 4; ++t) {
    abuf[0][t] = ldg8(ap + t * 16 * 256);
    abuf[1][t] = ldg8(ap + t * 16 * 256 + 32);
  }

  const float scl = 0.17677669529663687f;  // 1/sqrt(32)

  if (sblk < 2) {
    // ---- q/k: swapped operands -> C^T (cols in quartets, rows on ln) ----
    #pragma unroll
    for (int kt = 0; kt < 8; ++kt) {
      bf16x8 bb[4];
      #pragma unroll
      for (int ct = 0; ct < 4; ++ct)
        bb[ct] = *reinterpret_cast<const bf16x8*>(
            &bsh[(((wv & 1) * 4 + ct) * 8 + kt) * 512 + qd * 128 + ln * 8]);
      #pragma unroll
      for (int rt = 0; rt < 4; ++rt)
        #pragma unroll
        for (int ct = 0; ct < 4; ++ct)
          acc[rt][ct] = __builtin_amdgcn_mfma_f32_16x16x32_bf16(bb[ct], abuf[kt & 1][rt],
                                                                acc[rt][ct], 0, 0, 0);
      if (kt < 6) {
        #pragma unroll
        for (int t = 0; t < 4; ++t)
          abuf[kt & 1][t] = ldg8(ap + t * 16 * 256 + (kt + 2) * 32);
      }
    }
    #pragma unroll
    for (int ct = 0; ct < 4; ++ct) {
      int colg = colw + ct * 16 + qd * 4;
      float4 bq = *reinterpret_cast<const float4*>(qkvb + colg);
      int h = (colg >> 5) & 7;
      int d = colg & 31;
      #pragma unroll
      for (int rt = 0; rt < 4; ++rt) {
        int rowg = row0 + rt * 16 + ln;
        int bwin = rowg >> 8;
        int tok = rowg & 255;
        float v0 = acc[rt][ct][0] + bq.x, v1 = acc[rt][ct][1] + bq.y;
        float v2 = acc[rt][ct][2] + bq.z, v3 = acc[rt][ct][3] + bq.w;
        union { ushort_t u[4]; uint2 v; } pk;
        if (sblk == 0) {
          pk.u[0] = f2bf(v0 * scl); pk.u[1] = f2bf(v1 * scl);
          pk.u[2] = f2bf(v2 * scl); pk.u[3] = f2bf(v3 * scl);
          *reinterpret_cast<uint2*>(qws + ((size_t)((bwin * 8 + h) * 256 + tok) << 5) + d) = pk.v;
        } else {
          pk.u[0] = f2bf(v0); pk.u[1] = f2bf(v1);
          pk.u[2] = f2bf(v2); pk.u[3] = f2bf(v3);
          *reinterpret_cast<uint2*>(kws + (size_t)(bwin * 8 + h) * 8192 +
                                    (size_t)((tok >> 4) * 4 + (d >> 3)) * 128 +
                                    (tok & 15) * 8 + (d & 7)) = pk.v;
        }
      }
    }
  } else {
    // ---- v: normal operand order (tok in quartets) -> v_tiled ----
    #pragma unroll
    for (int kt = 0; kt < 8; ++kt) {
      bf16x8 bb[4];
      #pragma unroll
      for (int ct = 0; ct < 4; ++ct)
        bb[ct] = *reinterpret_cast<const bf16x8*>(
            &bsh[(((wv & 1) * 4 + ct) * 8 + kt) * 512 + qd * 128 + ln * 8]);
      #pragma unroll
      for (int rt = 0; rt < 4; ++rt)
        #pragma unroll
        for (int ct = 0; ct < 4; ++ct)
          acc[rt][ct] = __builtin_amdgcn_mfma_f32_16x16x32_bf16(abuf[kt & 1][rt], bb[ct],
                                                                acc[rt][ct], 0, 0, 0);
      if (kt < 6) {
        #pragma unroll
        for (int t = 0; t < 4; ++t)
          abuf[kt & 1][t] = ldg8(ap + t * 16 * 256 + (kt + 2) * 32);
      }
    }
    #pragma unroll
    for (int ct = 0; ct < 4; ++ct) {
      int colg = colw + ct * 16 + ln;
      float bcol = qkvb[colg];
      int h = (colg >> 5) & 7;
      int d = colg & 31;
      #pragma unroll
      for (int rt = 0; rt < 4; ++rt) {
        int rbase = row0 + rt * 16 + qd * 4;
        int bwin = rbase >> 8;
        int tok0 = rbase & 255;
        union { ushort_t u[4]; uint2 v; } pk;
        #pragma unroll
        for (int i = 0; i < 4; ++i) pk.u[i] = f2bf(acc[rt][ct][i] + bcol);
        size_t base = (size_t)(bwin * 8 + h) * 8192 +
                      (size_t)((tok0 >> 5) * 8 + (d >> 4) * 4 + ((tok0 >> 3) & 3)) * 128 +
                      (d & 15) * 8 + (tok0 & 7);
        *reinterpret_cast<uint2*>(vtws + base) = pk.v;
      }
    }
  }
}

// ---------------- kernel 3: windowed attention ------------------------------
__global__ __launch_bounds__(512, 4) void attn_kernel(
    const ushort_t* __restrict__ qws, const ushort_t* __restrict__ kt_,
    const ushort_t* __restrict__ vt_, const ushort_t* __restrict__ bm,
    ushort_t* __restrict__ aows) {
  __shared__ __align__(16) ushort_t lds_kv[16384];
  const int lane = threadIdx.x & 63;
  const int wv = threadIdx.x >> 6;
  const int ln = lane & 15, qd = lane >> 4;
  const int t = blockIdx.x;
  const int batch = t % 3;
  const int wh = t / 3;
  const int win = wh >> 3, h = wh & 7;
  const int bwin = batch * 64 + win;
  const int bh = bwin * 8 + h;

  {
    const char* kg = (const char*)(kt_ + (size_t)bh * 8192);
    const char* vg = (const char*)(vt_ + (size_t)bh * 8192);
    #pragma unroll
    for (int r = 0; r < 2; ++r) {
      int off = r * 8192 + wv * 1024;
      async_copy16(kg + off + lane * 16, (char*)lds_kv + off);
      async_copy16(vg + off + lane * 16, (char*)lds_kv + 16384 + off);
    }
  }
  __syncthreads();

  const ushort_t* qb = qws + (size_t)bh * 8192;
  const ushort_t* bmp = bm + ((size_t)(win * 8 + h) << 16);

  #pragma unroll
  for (int half = 0; half < 2; ++half) {
    const int m0 = half * 128 + wv * 16;

    bf16x8 qf = ldg8(qb + (m0 + ln) * 32 + qd * 8);
    floatx4 st[16];
    #pragma unroll
    for (int f = 0; f < 16; ++f) {
      bf16x8 kf = *reinterpret_cast<const bf16x8*>(&lds_kv[(f * 64 + lane) * 8]);
      floatx4 z = {0.f, 0.f, 0.f, 0.f};
      st[f] = __builtin_amdgcn_mfma_f32_16x16x32_bf16(kf, qf, z, 0, 0, 0);
    }

    // bias+mask: 8 dense uint4 loads (128B contiguous per lane)
    const ushort_t* bmr = bmp + ((m0 + ln) << 8) + qd * 64;
    uint4 braw[8];
    #pragma unroll
    for (int g = 0; g < 8; ++g)
      braw[g] = *reinterpret_cast<const uint4*>(bmr + g * 8);
    #pragma unroll
    for (int g = 0; g < 8; ++g) {
      st[2 * g][0]     += bf2f(braw[g].x);
      st[2 * g][1]     += bf2f(braw[g].x >> 16);
      st[2 * g][2]     += bf2f(braw[g].y);
      st[2 * g][3]     += bf2f(braw[g].y >> 16);
      st[2 * g + 1][0] += bf2f(braw[g].z);
      st[2 * g + 1][1] += bf2f(braw[g].z >> 16);
      st[2 * g + 1][2] += bf2f(braw[g].w);
      st[2 * g + 1][3] += bf2f(braw[g].w >> 16);
    }

    float mx = -1e30f;
    #pragma unroll
    for (int f = 0; f < 16; ++f)
      mx = fmaxf(mx, fmaxf(fmaxf(st[f][0], st[f][1]), fmaxf(st[f][2], st[f][3])));
    mx = fmaxf(mx, __shfl_xor(mx, 16, 64));
    mx = fmaxf(mx, __shfl_xor(mx, 32, 64));
    float sum = 0.f;
    #pragma unroll
    for (int f = 0; f < 16; ++f) {
      #pragma unroll
      for (int i = 0; i < 4; ++i) {
        float e = __expf(st[f][i] - mx);
        st[f][i] = e;
        sum += e;
      }
    }
    sum += __shfl_xor(sum, 16, 64);
    sum += __shfl_xor(sum, 32, 64);
    float inv = 1.0f / sum;

    uint2 pk[16];
    #pragma unroll
    for (int f = 0; f < 16; ++f) {
      union { ushort_t u[4]; uint2 v; } p;
      p.u[0] = f2bf(st[f][0]); p.u[1] = f2bf(st[f][1]);
      p.u[2] = f2bf(st[f][2]); p.u[3] = f2bf(st[f][3]);
      pk[f] = p.v;
    }

    float invr[4];
    #pragma unroll
    for (int i = 0; i < 4; ++i) invr[i] = __shfl(inv, qd * 4 + i, 16);

    const int lane_lo = ((qd & 1) << 5) + ln;
    const int lane_hi = lane_lo + 16;
    const bool fsel = (qd >> 1) != 0;
    floatx4 o[2];
    o[0] = floatx4{0.f, 0.f, 0.f, 0.f};
    o[1] = floatx4{0.f, 0.f, 0.f, 0.f};
    #pragma unroll
    for (int kt = 0; kt < 8; ++kt) {
      unsigned e0x = pk[2 * kt].x, e0y = pk[2 * kt].y;
      unsigned e1x = pk[2 * kt + 1].x, e1y = pk[2 * kt + 1].y;
      unsigned s0x = __shfl((int)e0x, lane_lo, 64), s0y = __shfl((int)e0y, lane_lo, 64);
      unsigned s1x = __shfl((int)e1x, lane_lo, 64), s1y = __shfl((int)e1y, lane_lo, 64);
      unsigned t0x = __shfl((int)e0x, lane_hi, 64), t0y = __shfl((int)e0y, lane_hi, 64);
      unsigned t1x = __shfl((int)e1x, lane_hi, 64), t1y = __shfl((int)e1y, lane_hi, 64);
      union { unsigned u[4]; bf16x8 v; } af;
      af.u[0] = fsel ? s1x : s0x;
      af.u[1] = fsel ? s1y : s0y;
      af.u[2] = fsel ? t1x : t0x;
      af.u[3] = fsel ? t1y : t0y;
      #pragma unroll
      for (int nt = 0; nt < 2; ++nt) {
        bf16x8 bv = *reinterpret_cast<const bf16x8*>(
            &lds_kv[8192 + ((kt * 8 + nt * 4 + qd) * 16 + ln) * 8]);
        o[nt] = __builtin_amdgcn_mfma_f32_16x16x32_bf16(af.v, bv, o[nt], 0, 0, 0);
      }
    }

    #pragma unroll
    for (int nt = 0; nt < 2; ++nt)
      #pragma unroll
      for (int i = 0; i < 4; ++i) {
        int tok = m0 + qd * 4 + i;
        aows[((size_t)(bwin * 256 + tok) << 8) + h * 32 + nt * 16 + ln] =
            f2bf(o[nt][i] * invr[i]);
      }
  }
}

// ---------------- kernel 4: output projection, C^T epilogue -----------------
__global__ __launch_bounds__(256) void proj_gemm(
    const ushort_t* __restrict__ a_, const ushort_t* __restrict__ wt,
    const float* __restrict__ pb, float* __restrict__ out) {
  __shared__ __align__(16) ushort_t bsh[128 * 256];   // 64 KB
  const int lane = threadIdx.x & 63;
  const int wv = threadIdx.x >> 6;
  const int ln = lane & 15, qd = lane >> 4;
  const int row0 = blockIdx.x * 128 + (wv >> 1) * 64;
  const int col0 = blockIdx.y * 128;
  const int colw = col0 + (wv & 1) * 64;

  {
    const char* g = (const char*)(wt + (size_t)col0 * 256);
    #pragma unroll
    for (int r = 0; r < 16; ++r) {
      int off = r * 4096 + wv * 1024;
      async_copy16(g + off + lane * 16, (char*)bsh + off);
    }
  }
  __syncthreads();

  floatx4 acc[4][4];
  #pragma unroll
  for (int rt = 0; rt < 4; ++rt)
    #pragma unroll
    for (int ct = 0; ct < 4; ++ct)
      acc[rt][ct] = floatx4{0.f, 0.f, 0.f, 0.f};

  const ushort_t* ap = a_ + (size_t)(row0 + ln) * 256 + qd * 8;
  bf16x8 abuf[2][4];
  #pragma unroll
  for (int t = 0; t < 4; ++t) {
    abuf[0][t] = ldg8(ap + t * 16 * 256);
    abuf[1][t] = ldg8(ap + t * 16 * 256 + 32);
  }

  #pragma unroll
  for (int kt = 0; kt < 8; ++kt) {
    bf16x8 bb[4];
    #pragma unroll
    for (int ct = 0; ct < 4; ++ct)
      bb[ct] = *reinterpret_cast<const bf16x8*>(
          &bsh[(((wv & 1) * 4 + ct) * 8 + kt) * 512 + qd * 128 + ln * 8]);
    #pragma unroll
    for (int rt = 0; rt < 4; ++rt)
      #pragma unroll
      for (int ct = 0; ct < 4; ++ct)
        acc[rt][ct] = __builtin_amdgcn_mfma_f32_16x16x32_bf16(bb[ct], abuf[kt & 1][rt],
                                                              acc[rt][ct], 0, 0, 0);
    if (kt < 6) {
      #pragma unroll
      for (int t = 0; t < 4; ++t)
        abuf[kt & 1][t] = ldg8(ap + t * 16 * 256 + (kt + 2) * 32);
    }
  }

  #pragma unroll
  for (int ct = 0; ct < 4; ++ct) {
    int colg = colw + ct * 16 + qd * 4;
    float4 bq = *reinterpret_cast<const float4*>(pb + colg);
    #pragma unroll
    for (int rt = 0; rt < 4; ++rt) {
      int rowg = row0 + rt * 16 + ln;
      float4 o;
      o.x = acc[rt][ct][0] + bq.x;
      o.y = acc[rt][ct][1] + bq.y;
      o.z = acc[rt][ct][2] + bq.z;
      o.w = acc[rt][ct][3] + bq.w;
      *reinterpret_cast<float4*>(out + (size_t)rowg * 256 + colg) = o;
    }
  }
}

// ---------------- launch ----------------------------------------------------
extern "C" void kernel_launch(void* const* d_in, const int* in_sizes, int n_in,
                              void* d_out, int out_size, void* d_ws, size_t ws_size,
                              hipStream_t stream) {
  const float* x      = (const float*)d_in[0];
  const float* mask   = (const float*)d_in[1];
  const float* qkv_w  = (const float*)d_in[2];
  const float* qkv_b  = (const float*)d_in[3];
  const float* proj_w = (const float*)d_in[4];
  const float* proj_b = (const float*)d_in[5];
  const float* table  = (const float*)d_in[6];
  const int*   idx    = (const int*)d_in[7];
  float* out = (float*)d_out;

  char* ws = (char*)d_ws;
  const size_t SZ = (size_t)MROWS * CDIM * 2;  // 25165824 B per bf16 buffer
  ushort_t* xbf  = (ushort_t*)(ws);
  ushort_t* qws  = (ushort_t*)(ws + SZ);
  ushort_t* kws  = (ushort_t*)(ws + 2 * SZ);   // k_tiled
  ushort_t* vtws = (ushort_t*)(ws + 3 * SZ);   // v_tiled
  ushort_t* aows = (ushort_t*)(ws + 4 * SZ);
  ushort_t* bmws = (ushort_t*)(ws + 5 * SZ);                    // 64 MB bf16 tiled
  ushort_t* wqkvbf  = (ushort_t*)(ws + 5 * SZ + 67108864);      // tiled 768x256 bf16
  ushort_t* wprojbf = (ushort_t*)(ws + 5 * SZ + 67108864 + 393216);

  cvt_f32_bf16<<<dim3(6144), dim3(256), 0, stream>>>(x, xbf, 12582912 / 8);
  cvt_tile_w<<<dim3(96), dim3(256), 0, stream>>>(qkv_w, wqkvbf, 768 * 32);
  cvt_tile_w<<<dim3(32), dim3(256), 0, stream>>>(proj_w, wprojbf, 256 * 32);
  bm_prep<<<dim3(64, 256), dim3(256), 0, stream>>>(idx, table, mask, bmws);
  qkv_gemm<<<dim3(384, 6), dim3(256), 0, stream>>>(xbf, wqkvbf, qkv_b, qws, kws, vtws);
  attn_kernel<<<dim3(1536), dim3(512), 0, stream>>>(qws, kws, vtws, bmws, aows);
  proj_gemm<<<dim3(384, 2), dim3(256), 0, stream>>>(aows, wprojbf, proj_b, out);
}